// Round 5
// baseline (334.786 us; speedup 1.0000x reference)
//
#include <hip/hip_runtime.h>

typedef __attribute__((ext_vector_type(8))) short short8;
typedef __attribute__((ext_vector_type(4))) float floatx4;

#define CIN    192
#define COUTN  192
#define HWDIM  56
#define HWSZ   (56*56)
#define KWT    1728
#define PH     58
#define NCHUNK 6

// ws: wpack [cc 6][off 9][m 192][c 32] bf16  -> 768 16B-chunks per (cc,off) slab
#define WPACK_SHORTS (6u*9u*192u*32u)
#define WS_NEEDED    ((size_t)WPACK_SHORTS * 2u)

__device__ __forceinline__ short f2bf(float f) {
    union { float f; unsigned u; } v; v.f = f;
    unsigned u = v.u + 0x7FFFu + ((v.u >> 16) & 1u);  // RNE
    return (short)(u >> 16);
}

// ---------------- pack weights to [cc][off][m 192][c 32] bf16 ----------------
__global__ __launch_bounds__(256)
void pack_w(const float* __restrict__ w, short* __restrict__ wp) {
    int idx = blockIdx.x * 256 + threadIdx.x;          // one thread per 16B chunk
    const int TOT = 6 * 9 * 192 * 4;
    if (idx >= TOT) return;
    int cg = idx & 3;
    int m  = (idx >> 2) % 192;
    int t  = idx / (4 * 192);                          // t = cc*9 + off
    int off = t % 9;
    int cc  = t / 9;
    short8 v;
#pragma unroll
    for (int k = 0; k < 8; ++k)
        v[k] = f2bf(w[(size_t)m * KWT + (cc * 32 + cg * 8 + k) * 9 + off]);
    *(short8*)(wp + (size_t)idx * 8) = v;
}

// ---------------- fused conv: m=192, n=224 (4 rows), stage f32->bf16 in-kernel ----------------
__global__ __launch_bounds__(512, 4)
void conv_fused(const float* __restrict__ x, const short* __restrict__ wp,
                const float* __restrict__ bias, float* __restrict__ out) {
    __shared__ __align__(16) short sh[6 * PH * 32];    // 22,272 B halo [y6][x58][c32] swizzled

    const int tid  = threadIdx.x;
    const int gh0  = blockIdx.x * 4;                   // 14 tiles of 4 output rows
    const int bb   = blockIdx.y;
    const int lane = tid & 63;
    const int wave = tid >> 6;                         // 8 waves: 4 m-groups x 2 n-halves
    const int wm   = wave >> 1;                        // 0..3 -> cout base wm*48
    const int wn   = wave & 1;                         // 0..1 -> px base wn*112
    const int g    = lane >> 4;
    const int col  = lane & 15;

    int pb[7];                                         // halo px index per n-tile
#pragma unroll
    for (int nt = 0; nt < 7; ++nt) {
        int l = wn * 112 + nt * 16 + col;
        pb[nt] = (l / 56) * PH + (l % 56);
    }

    floatx4 acc[3][7];
#pragma unroll
    for (int mt = 0; mt < 3; ++mt)
#pragma unroll
        for (int nt = 0; nt < 7; ++nt)
            acc[mt][nt] = (floatx4){0.f, 0.f, 0.f, 0.f};

    const short8* wpk = (const short8*)wp;
    const int mchunk = (wm * 48 + col) * 4 + g;        // this lane's m-chunk (mt adds 16*4)

    for (int cc = 0; cc < NCHUNK; ++cc) {
        if (cc) __syncthreads();                       // prior compute done before overwrite

        // ---- stage halo 6x58 px x 32 ch: 1392 slots, 8-ch gather -> one b128 write ----
#pragma unroll
        for (int it = 0; it < 3; ++it) {
            int slot = it * 512 + tid;
            if (slot < 1392) {
                int xx = slot % 58;
                int t  = slot / 58;
                int y  = t % 6;
                int cg = t / 6;                        // 8-ch group 0..3
                int gh = gh0 + y - 1;
                int gw = xx - 1;
                short8 v = (short8){0, 0, 0, 0, 0, 0, 0, 0};
                if (((unsigned)gh < 56u) & ((unsigned)gw < 56u)) {
                    const float* src = x + ((size_t)(bb * CIN + cc * 32 + cg * 8) * HWSZ) + gh * HWDIM + gw;
#pragma unroll
                    for (int k = 0; k < 8; ++k) v[k] = f2bf(src[(size_t)k * HWSZ]);
                }
                int p = y * PH + xx;
                *(short8*)&sh[(((p << 2) | (cg ^ ((p >> 1) & 3))) << 3)] = v;
            }
        }
        __syncthreads();

        // ---- compute: 9 offsets, depth-1 A-frag pipeline, 3 mt x 7 nt MFMAs each ----
        const int wb = cc * 9;                         // slab index; *768 chunks per slab
        short8 afr[3], nafr[3];
#pragma unroll
        for (int mt = 0; mt < 3; ++mt)
            afr[mt] = wpk[(size_t)wb * 768 + mchunk + mt * 64];
#pragma unroll
        for (int off = 0; off < 9; ++off) {
            const int di = off / 3, dj = off % 3;
            if (off < 8) {
#pragma unroll
                for (int mt = 0; mt < 3; ++mt)
                    nafr[mt] = wpk[(size_t)(wb + off + 1) * 768 + mchunk + mt * 64];
            }
#pragma unroll
            for (int nt = 0; nt < 7; ++nt) {
                int p = pb[nt] + di * PH + dj;
                short8 bfr = *(const short8*)&sh[(((p << 2) | (g ^ ((p >> 1) & 3))) << 3)];
                acc[0][nt] = __builtin_amdgcn_mfma_f32_16x16x32_bf16(afr[0], bfr, acc[0][nt], 0, 0, 0);
                acc[1][nt] = __builtin_amdgcn_mfma_f32_16x16x32_bf16(afr[1], bfr, acc[1][nt], 0, 0, 0);
                acc[2][nt] = __builtin_amdgcn_mfma_f32_16x16x32_bf16(afr[2], bfr, acc[2][nt], 0, 0, 0);
            }
#pragma unroll
            for (int mt = 0; mt < 3; ++mt) afr[mt] = nafr[mt];
        }
    }

    // ---- epilogue: D row = g*4 + r, col = lane&15 ----
#pragma unroll
    for (int mt = 0; mt < 3; ++mt) {
        int o = wm * 48 + mt * 16 + g * 4;
        float b0 = bias[o], b1 = bias[o + 1], b2 = bias[o + 2], b3 = bias[o + 3];
#pragma unroll
        for (int nt = 0; nt < 7; ++nt) {
            int l  = wn * 112 + nt * 16 + col;
            int h  = gh0 + l / 56;
            int ww = l % 56;
            size_t base = ((size_t)(bb * COUTN + o) * HWDIM + h) * HWDIM + ww;
            floatx4 v = acc[mt][nt];
            out[base]                    = v[0] + b0;
            out[base + (size_t)HWSZ]     = v[1] + b1;
            out[base + (size_t)2 * HWSZ] = v[2] + b2;
            out[base + (size_t)3 * HWSZ] = v[3] + b3;
        }
    }
}

// ---------------- fallback if ws too small (reads w directly) ----------------
__global__ __launch_bounds__(256, 2)
void conv3x3_fb(const float* __restrict__ x, const float* __restrict__ w,
                const float* __restrict__ bias, float* __restrict__ out) {
    __shared__ __align__(16) short sh_halo[6 * 58 * 32];
    __shared__ __align__(16) short sh_w[9 * 64 * 32];
    const int tid = threadIdx.x;
    const int gh0 = blockIdx.x * 4;
    const int o0  = blockIdx.y * 64;
    const int bb  = blockIdx.z;
    const int lane = tid & 63, wave = tid >> 6;
    const int wm = wave >> 1, wn = wave & 1;
    const int g = lane >> 4, col = lane & 15;
    int ly[7], lx[7];
#pragma unroll
    for (int nt = 0; nt < 7; ++nt) {
        int l = wn * 112 + nt * 16 + col;
        ly[nt] = l / 56; lx[nt] = l % 56;
    }
    floatx4 acc[2][7];
#pragma unroll
    for (int mt = 0; mt < 2; ++mt)
#pragma unroll
        for (int nt = 0; nt < 7; ++nt) acc[mt][nt] = (floatx4){0.f,0.f,0.f,0.f};
    for (int cc = 0; cc < NCHUNK; ++cc) {
        const int c0 = cc * 32;
        if (cc) __syncthreads();
        for (int i = tid; i < 4 * 6 * 58; i += 256) {
            int xx = i % 58, r = i / 58, y = r % 6, cg = r / 6;
            int gh = gh0 + y - 1, gw = xx - 1;
            bool ok = ((unsigned)gh < 56u) & ((unsigned)gw < 56u);
            const float* src = x + ((size_t)(bb * CIN + c0 + cg * 8) * HWDIM + gh) * HWDIM + gw;
            short8 v;
#pragma unroll
            for (int k = 0; k < 8; ++k) v[k] = f2bf(ok ? src[k * HWSZ] : 0.f);
            *(short8*)&sh_halo[(y * 58 + xx) * 32 + ((cg ^ ((xx >> 1) & 3)) << 3)] = v;
        }
        for (int i = tid; i < 9 * 64 * 4; i += 256) {
            int cg = i & 3, off = (i >> 2) % 9, m = i / 36;
            const float* src = w + (size_t)(o0 + m) * KWT + (c0 + cg * 8) * 9 + off;
            short8 v;
#pragma unroll
            for (int k = 0; k < 8; ++k) v[k] = f2bf(src[k * 9]);
            *(short8*)&sh_w[(off * 64 + m) * 32 + ((cg ^ ((m >> 1) & 3)) << 3)] = v;
        }
        __syncthreads();
#pragma unroll
        for (int off = 0; off < 9; ++off) {
            const int di = off / 3, dj = off % 3;
            short8 a[2];
#pragma unroll
            for (int mt = 0; mt < 2; ++mt) {
                int m = wm * 32 + mt * 16 + col;
                a[mt] = *(const short8*)&sh_w[(off * 64 + m) * 32 + ((g ^ ((m >> 1) & 3)) << 3)];
            }
#pragma unroll
            for (int nt = 0; nt < 7; ++nt) {
                int yy = ly[nt] + di, xpp = lx[nt] + dj;
                short8 bfr = *(const short8*)&sh_halo[(yy * 58 + xpp) * 32 + ((g ^ ((xpp >> 1) & 3)) << 3)];
                acc[0][nt] = __builtin_amdgcn_mfma_f32_16x16x32_bf16(a[0], bfr, acc[0][nt], 0, 0, 0);
                acc[1][nt] = __builtin_amdgcn_mfma_f32_16x16x32_bf16(a[1], bfr, acc[1][nt], 0, 0, 0);
            }
        }
    }
#pragma unroll
    for (int mt = 0; mt < 2; ++mt) {
        int o = o0 + wm * 32 + mt * 16 + g * 4;
#pragma unroll
        for (int nt = 0; nt < 7; ++nt) {
            int l = wn * 112 + nt * 16 + col;
            int h = gh0 + l / 56, ww = l % 56;
            size_t base = ((size_t)(bb * COUTN + o) * HWDIM + h) * HWDIM + ww;
            floatx4 v = acc[mt][nt];
#pragma unroll
            for (int r2 = 0; r2 < 4; ++r2)
                out[base + (size_t)r2 * HWSZ] = v[r2] + bias[o + r2];
        }
    }
}

extern "C" void kernel_launch(void* const* d_in, const int* in_sizes, int n_in,
                              void* d_out, int out_size, void* d_ws, size_t ws_size,
                              hipStream_t stream) {
    const float* x  = (const float*)d_in[0];
    const float* wt = (const float*)d_in[1];
    const float* bi = (const float*)d_in[2];
    float* out = (float*)d_out;

    if (ws_size >= WS_NEEDED) {
        short* wpk = (short*)d_ws;
        int tot = 6 * 9 * 192 * 4;
        pack_w<<<(tot + 255) / 256, 256, 0, stream>>>(wt, wpk);
        conv_fused<<<dim3(14, 32), dim3(512), 0, stream>>>(x, wpk, bi, out);
    } else {
        conv3x3_fb<<<dim3(14, 3, 32), dim3(256), 0, stream>>>(x, wt, bi, out);
    }
}

// Round 6
// 318.567 us; speedup vs baseline: 1.0509x; 1.0509x over previous
//
#include <hip/hip_runtime.h>

typedef __attribute__((ext_vector_type(8))) short short8;
typedef __attribute__((ext_vector_type(4))) float floatx4;

#define CIN    192
#define COUTN  192
#define HWDIM  56
#define HWSZ   (56*56)
#define KWT    1728
#define PH     58
#define NCHUNK 6

// ws: wpack [cc 6][off 9][m 192][c 32] bf16  -> 768 16B-chunks per (cc,off) slab
#define WPACK_SHORTS (6u*9u*192u*32u)
#define WS_NEEDED    ((size_t)WPACK_SHORTS * 2u)

__device__ __forceinline__ short f2bf(float f) {
    union { float f; unsigned u; } v; v.f = f;
    unsigned u = v.u + 0x7FFFu + ((v.u >> 16) & 1u);  // RNE
    return (short)(u >> 16);
}

// ---------------- pack weights to [cc][off][m 192][c 32] bf16 ----------------
__global__ __launch_bounds__(256)
void pack_w(const float* __restrict__ w, short* __restrict__ wp) {
    int idx = blockIdx.x * 256 + threadIdx.x;          // one thread per 16B chunk
    const int TOT = 6 * 9 * 192 * 4;
    if (idx >= TOT) return;
    int cg = idx & 3;
    int m  = (idx >> 2) % 192;
    int t  = idx / (4 * 192);                          // t = cc*9 + off
    int off = t % 9;
    int cc  = t / 9;
    short8 v;
#pragma unroll
    for (int k = 0; k < 8; ++k)
        v[k] = f2bf(w[(size_t)m * KWT + (cc * 32 + cg * 8 + k) * 9 + off]);
    *(short8*)(wp + (size_t)idx * 8) = v;
}

// ---------------- fused conv: m=192, n=224 (4 rows), stage f32->bf16 in-kernel ----------------
// 512 thr = 8 waves. amdgpu_waves_per_eu(4) -> >=16 waves/CU -> VGPR cap 128 (2 blocks/CU).
// NOTE: __launch_bounds__(512,4) was honored as 4 blocks/CU -> 64-VGPR cap -> acc spill (R5).
__global__ __launch_bounds__(512) __attribute__((amdgpu_waves_per_eu(4)))
void conv_fused(const float* __restrict__ x, const short* __restrict__ wp,
                const float* __restrict__ bias, float* __restrict__ out) {
    __shared__ __align__(16) short sh[6 * PH * 32];    // 22,272 B halo [y6][x58][c32] swizzled

    const int tid  = threadIdx.x;
    const int gh0  = blockIdx.x * 4;                   // 14 tiles of 4 output rows
    const int bb   = blockIdx.y;
    const int lane = tid & 63;
    const int wave = tid >> 6;                         // 8 waves: 4 m-groups x 2 n-halves
    const int wm   = wave >> 1;                        // 0..3 -> cout base wm*48
    const int wn   = wave & 1;                         // 0..1 -> px base wn*112
    const int g    = lane >> 4;
    const int col  = lane & 15;

    int pb[7];                                         // halo px index per n-tile
#pragma unroll
    for (int nt = 0; nt < 7; ++nt) {
        int l = wn * 112 + nt * 16 + col;
        pb[nt] = (l / 56) * PH + (l % 56);
    }

    floatx4 acc[3][7];
#pragma unroll
    for (int mt = 0; mt < 3; ++mt)
#pragma unroll
        for (int nt = 0; nt < 7; ++nt)
            acc[mt][nt] = (floatx4){0.f, 0.f, 0.f, 0.f};

    const short8* wpk = (const short8*)wp;
    const int mchunk = (wm * 48 + col) * 4 + g;        // lane's m-chunk (mt adds 64)

    for (int cc = 0; cc < NCHUNK; ++cc) {
        if (cc) __syncthreads();                       // prior compute done before overwrite

        // ---- stage halo 6x58 px x 32 ch: 1392 slots, 8-ch gather -> one b128 write ----
#pragma unroll
        for (int it = 0; it < 3; ++it) {
            int slot = it * 512 + tid;
            if (slot < 1392) {
                int xx = slot % 58;
                int t  = slot / 58;
                int y  = t % 6;
                int cg = t / 6;                        // 8-ch group 0..3
                int gh = gh0 + y - 1;
                int gw = xx - 1;
                short8 v = (short8){0, 0, 0, 0, 0, 0, 0, 0};
                if (((unsigned)gh < 56u) & ((unsigned)gw < 56u)) {
                    const float* src = x + ((size_t)(bb * CIN + cc * 32 + cg * 8) * HWSZ) + gh * HWDIM + gw;
#pragma unroll
                    for (int k = 0; k < 8; ++k) v[k] = f2bf(src[(size_t)k * HWSZ]);
                }
                int p = y * PH + xx;
                *(short8*)&sh[(((p << 2) | (cg ^ ((p >> 1) & 3))) << 3)] = v;
            }
        }
        __syncthreads();

        // ---- compute: 9 offsets, 3 mt x 7 nt MFMAs each ----
        const size_t wb = (size_t)cc * 9 * 768;        // 768 chunks per (cc,off) slab
#pragma unroll
        for (int off = 0; off < 9; ++off) {
            const int di = off / 3, dj = off % 3;
            short8 afr[3];
#pragma unroll
            for (int mt = 0; mt < 3; ++mt)
                afr[mt] = wpk[wb + (size_t)off * 768 + mchunk + mt * 64];
#pragma unroll
            for (int nt = 0; nt < 7; ++nt) {
                int p = pb[nt] + di * PH + dj;
                short8 bfr = *(const short8*)&sh[(((p << 2) | (g ^ ((p >> 1) & 3))) << 3)];
                acc[0][nt] = __builtin_amdgcn_mfma_f32_16x16x32_bf16(afr[0], bfr, acc[0][nt], 0, 0, 0);
                acc[1][nt] = __builtin_amdgcn_mfma_f32_16x16x32_bf16(afr[1], bfr, acc[1][nt], 0, 0, 0);
                acc[2][nt] = __builtin_amdgcn_mfma_f32_16x16x32_bf16(afr[2], bfr, acc[2][nt], 0, 0, 0);
            }
        }
    }

    // ---- epilogue: D row = g*4 + r, col = lane&15 ----
#pragma unroll
    for (int mt = 0; mt < 3; ++mt) {
        int o = wm * 48 + mt * 16 + g * 4;
        float b0 = bias[o], b1 = bias[o + 1], b2 = bias[o + 2], b3 = bias[o + 3];
#pragma unroll
        for (int nt = 0; nt < 7; ++nt) {
            int l  = wn * 112 + nt * 16 + col;
            int h  = gh0 + l / 56;
            int ww = l % 56;
            size_t base = ((size_t)(bb * COUTN + o) * HWDIM + h) * HWDIM + ww;
            floatx4 v = acc[mt][nt];
            out[base]                    = v[0] + b0;
            out[base + (size_t)HWSZ]     = v[1] + b1;
            out[base + (size_t)2 * HWSZ] = v[2] + b2;
            out[base + (size_t)3 * HWSZ] = v[3] + b3;
        }
    }
}

// ---------------- fallback if ws too small (reads w directly) ----------------
__global__ __launch_bounds__(256, 2)
void conv3x3_fb(const float* __restrict__ x, const float* __restrict__ w,
                const float* __restrict__ bias, float* __restrict__ out) {
    __shared__ __align__(16) short sh_halo[6 * 58 * 32];
    __shared__ __align__(16) short sh_w[9 * 64 * 32];
    const int tid = threadIdx.x;
    const int gh0 = blockIdx.x * 4;
    const int o0  = blockIdx.y * 64;
    const int bb  = blockIdx.z;
    const int lane = tid & 63, wave = tid >> 6;
    const int wm = wave >> 1, wn = wave & 1;
    const int g = lane >> 4, col = lane & 15;
    int ly[7], lx[7];
#pragma unroll
    for (int nt = 0; nt < 7; ++nt) {
        int l = wn * 112 + nt * 16 + col;
        ly[nt] = l / 56; lx[nt] = l % 56;
    }
    floatx4 acc[2][7];
#pragma unroll
    for (int mt = 0; mt < 2; ++mt)
#pragma unroll
        for (int nt = 0; nt < 7; ++nt) acc[mt][nt] = (floatx4){0.f,0.f,0.f,0.f};
    for (int cc = 0; cc < NCHUNK; ++cc) {
        const int c0 = cc * 32;
        if (cc) __syncthreads();
        for (int i = tid; i < 4 * 6 * 58; i += 256) {
            int xx = i % 58, r = i / 58, y = r % 6, cg = r / 6;
            int gh = gh0 + y - 1, gw = xx - 1;
            bool ok = ((unsigned)gh < 56u) & ((unsigned)gw < 56u);
            const float* src = x + ((size_t)(bb * CIN + c0 + cg * 8) * HWDIM + gh) * HWDIM + gw;
            short8 v;
#pragma unroll
            for (int k = 0; k < 8; ++k) v[k] = f2bf(ok ? src[k * HWSZ] : 0.f);
            *(short8*)&sh_halo[(y * 58 + xx) * 32 + ((cg ^ ((xx >> 1) & 3)) << 3)] = v;
        }
        for (int i = tid; i < 9 * 64 * 4; i += 256) {
            int cg = i & 3, off = (i >> 2) % 9, m = i / 36;
            const float* src = w + (size_t)(o0 + m) * KWT + (c0 + cg * 8) * 9 + off;
            short8 v;
#pragma unroll
            for (int k = 0; k < 8; ++k) v[k] = f2bf(src[k * 9]);
            *(short8*)&sh_w[(off * 64 + m) * 32 + ((cg ^ ((m >> 1) & 3)) << 3)] = v;
        }
        __syncthreads();
#pragma unroll
        for (int off = 0; off < 9; ++off) {
            const int di = off / 3, dj = off % 3;
            short8 a[2];
#pragma unroll
            for (int mt = 0; mt < 2; ++mt) {
                int m = wm * 32 + mt * 16 + col;
                a[mt] = *(const short8*)&sh_w[(off * 64 + m) * 32 + ((g ^ ((m >> 1) & 3)) << 3)];
            }
#pragma unroll
            for (int nt = 0; nt < 7; ++nt) {
                int yy = ly[nt] + di, xpp = lx[nt] + dj;
                short8 bfr = *(const short8*)&sh_halo[(yy * 58 + xpp) * 32 + ((g ^ ((xpp >> 1) & 3)) << 3)];
                acc[0][nt] = __builtin_amdgcn_mfma_f32_16x16x32_bf16(a[0], bfr, acc[0][nt], 0, 0, 0);
                acc[1][nt] = __builtin_amdgcn_mfma_f32_16x16x32_bf16(a[1], bfr, acc[1][nt], 0, 0, 0);
            }
        }
    }
#pragma unroll
    for (int mt = 0; mt < 2; ++mt) {
        int o = o0 + wm * 32 + mt * 16 + g * 4;
#pragma unroll
        for (int nt = 0; nt < 7; ++nt) {
            int l = wn * 112 + nt * 16 + col;
            int h = gh0 + l / 56, ww = l % 56;
            size_t base = ((size_t)(bb * COUTN + o) * HWDIM + h) * HWDIM + ww;
            floatx4 v = acc[mt][nt];
#pragma unroll
            for (int r2 = 0; r2 < 4; ++r2)
                out[base + (size_t)r2 * HWSZ] = v[r2] + bias[o + r2];
        }
    }
}

extern "C" void kernel_launch(void* const* d_in, const int* in_sizes, int n_in,
                              void* d_out, int out_size, void* d_ws, size_t ws_size,
                              hipStream_t stream) {
    const float* x  = (const float*)d_in[0];
    const float* wt = (const float*)d_in[1];
    const float* bi = (const float*)d_in[2];
    float* out = (float*)d_out;

    if (ws_size >= WS_NEEDED) {
        short* wpk = (short*)d_ws;
        int tot = 6 * 9 * 192 * 4;
        pack_w<<<(tot + 255) / 256, 256, 0, stream>>>(wt, wpk);
        conv_fused<<<dim3(14, 32), dim3(512), 0, stream>>>(x, wpk, bi, out);
    } else {
        conv3x3_fb<<<dim3(14, 3, 32), dim3(256), 0, stream>>>(x, wt, bi, out);
    }
}

// Round 7
// 217.677 us; speedup vs baseline: 1.5380x; 1.4635x over previous
//
#include <hip/hip_runtime.h>

typedef __attribute__((ext_vector_type(8))) short short8;
typedef __attribute__((ext_vector_type(4))) float floatx4;

#define CIN    192
#define COUTN  192
#define HWDIM  56
#define HWSZ   (56*56)
#define KWT    1728
#define PH     58
#define NCHUNK 6

// ws: wpack [cc 6][off 9][m 192][c 32] bf16  -> 768 16B-chunks per (cc,off) slab
#define WPACK_SHORTS (6u*9u*192u*32u)
#define WS_NEEDED    ((size_t)WPACK_SHORTS * 2u)

__device__ __forceinline__ short f2bf(float f) {
    union { float f; unsigned u; } v; v.f = f;
    unsigned u = v.u + 0x7FFFu + ((v.u >> 16) & 1u);  // RNE
    return (short)(u >> 16);
}

// ---------------- pack weights to [cc][off][m 192][c 32] bf16 ----------------
__global__ __launch_bounds__(256)
void pack_w(const float* __restrict__ w, short* __restrict__ wp) {
    int idx = blockIdx.x * 256 + threadIdx.x;          // one thread per 16B chunk
    const int TOT = 6 * 9 * 192 * 4;
    if (idx >= TOT) return;
    int cg = idx & 3;
    int m  = (idx >> 2) % 192;
    int t  = idx / (4 * 192);                          // t = cc*9 + off
    int off = t % 9;
    int cc  = t / 9;
    short8 v;
#pragma unroll
    for (int k = 0; k < 8; ++k)
        v[k] = f2bf(w[(size_t)m * KWT + (cc * 32 + cg * 8 + k) * 9 + off]);
    *(short8*)(wp + (size_t)idx * 8) = v;
}

// ---------------- fused conv: 256 thr, m=192, n=112 (2 rows), 4-row halo ----------------
// 256-thread blocks: __launch_bounds__(256,2) gave 116 VGPR spill-free in R3.
// 512-thread blocks capped VGPR at 64 and spilled the accumulators (R5/R6) — avoid.
__global__ __launch_bounds__(256, 2)
void conv_fused(const float* __restrict__ x, const short* __restrict__ wp,
                const float* __restrict__ bias, float* __restrict__ out) {
    __shared__ __align__(16) short sh[4 * PH * 32];    // 14,848 B halo [y4][x58][c32] swizzled

    const int tid  = threadIdx.x;
    const int gh0  = blockIdx.x * 2;                   // 28 tiles of 2 output rows
    const int bb   = blockIdx.y;
    const int lane = tid & 63;
    const int wave = tid >> 6;                         // 4 waves = 4 cout groups of 48
    const int g    = lane >> 4;
    const int col  = lane & 15;

    int pb[7];                                         // halo px index per n-tile (n=112 shared)
#pragma unroll
    for (int nt = 0; nt < 7; ++nt) {
        int l = nt * 16 + col;
        pb[nt] = (l / 56) * PH + (l % 56);
    }

    floatx4 acc[3][7];
#pragma unroll
    for (int mt = 0; mt < 3; ++mt)
#pragma unroll
        for (int nt = 0; nt < 7; ++nt)
            acc[mt][nt] = (floatx4){0.f, 0.f, 0.f, 0.f};

    const short8* wpk = (const short8*)wp;
    const int mchunk = (wave * 48 + col) * 4 + g;      // lane's m-chunk (mt adds 64)

    for (int cc = 0; cc < NCHUNK; ++cc) {
        if (cc) __syncthreads();                       // prior compute done before overwrite

        // ---- stage halo 4x58 px x 32 ch: 928 slots, 8-ch gather -> one b128 write ----
#pragma unroll
        for (int it = 0; it < 4; ++it) {
            int slot = it * 256 + tid;
            if (slot < 928) {
                int xx = slot % 58;
                int t  = slot / 58;
                int y  = t & 3;
                int cg = t >> 2;                       // 8-ch group 0..3
                int gh = gh0 + y - 1;
                int gw = xx - 1;
                short8 v = (short8){0, 0, 0, 0, 0, 0, 0, 0};
                if (((unsigned)gh < 56u) & ((unsigned)gw < 56u)) {
                    const float* src = x + ((size_t)(bb * CIN + cc * 32 + cg * 8) * HWSZ) + gh * HWDIM + gw;
#pragma unroll
                    for (int k = 0; k < 8; ++k) v[k] = f2bf(src[(size_t)k * HWSZ]);
                }
                int p = y * PH + xx;
                *(short8*)&sh[(((p << 2) | (cg ^ ((p >> 1) & 3))) << 3)] = v;
            }
        }
        __syncthreads();

        // ---- compute: 9 offsets, 3 mt x 7 nt MFMAs each ----
        const size_t wb = (size_t)cc * 9 * 768;        // 768 chunks per (cc,off) slab
#pragma unroll
        for (int off = 0; off < 9; ++off) {
            const int di = off / 3, dj = off % 3;
            short8 afr[3];
#pragma unroll
            for (int mt = 0; mt < 3; ++mt)
                afr[mt] = wpk[wb + (size_t)off * 768 + mchunk + mt * 64];
#pragma unroll
            for (int nt = 0; nt < 7; ++nt) {
                int p = pb[nt] + di * PH + dj;
                short8 bfr = *(const short8*)&sh[(((p << 2) | (g ^ ((p >> 1) & 3))) << 3)];
                acc[0][nt] = __builtin_amdgcn_mfma_f32_16x16x32_bf16(afr[0], bfr, acc[0][nt], 0, 0, 0);
                acc[1][nt] = __builtin_amdgcn_mfma_f32_16x16x32_bf16(afr[1], bfr, acc[1][nt], 0, 0, 0);
                acc[2][nt] = __builtin_amdgcn_mfma_f32_16x16x32_bf16(afr[2], bfr, acc[2][nt], 0, 0, 0);
            }
        }
    }

    // ---- epilogue: D row = g*4 + r, col = lane&15 ----
#pragma unroll
    for (int mt = 0; mt < 3; ++mt) {
        int o = wave * 48 + mt * 16 + g * 4;
        float b0 = bias[o], b1 = bias[o + 1], b2 = bias[o + 2], b3 = bias[o + 3];
#pragma unroll
        for (int nt = 0; nt < 7; ++nt) {
            int l  = nt * 16 + col;
            int h  = gh0 + l / 56;
            int ww = l % 56;
            size_t base = ((size_t)(bb * COUTN + o) * HWDIM + h) * HWDIM + ww;
            floatx4 v = acc[mt][nt];
            out[base]                    = v[0] + b0;
            out[base + (size_t)HWSZ]     = v[1] + b1;
            out[base + (size_t)2 * HWSZ] = v[2] + b2;
            out[base + (size_t)3 * HWSZ] = v[3] + b3;
        }
    }
}

// ---------------- fallback if ws too small (reads w directly) ----------------
__global__ __launch_bounds__(256, 2)
void conv3x3_fb(const float* __restrict__ x, const float* __restrict__ w,
                const float* __restrict__ bias, float* __restrict__ out) {
    __shared__ __align__(16) short sh_halo[6 * 58 * 32];
    __shared__ __align__(16) short sh_w[9 * 64 * 32];
    const int tid = threadIdx.x;
    const int gh0 = blockIdx.x * 4;
    const int o0  = blockIdx.y * 64;
    const int bb  = blockIdx.z;
    const int lane = tid & 63, wave = tid >> 6;
    const int wm = wave >> 1, wn = wave & 1;
    const int g = lane >> 4, col = lane & 15;
    int ly[7], lx[7];
#pragma unroll
    for (int nt = 0; nt < 7; ++nt) {
        int l = wn * 112 + nt * 16 + col;
        ly[nt] = l / 56; lx[nt] = l % 56;
    }
    floatx4 acc[2][7];
#pragma unroll
    for (int mt = 0; mt < 2; ++mt)
#pragma unroll
        for (int nt = 0; nt < 7; ++nt) acc[mt][nt] = (floatx4){0.f,0.f,0.f,0.f};
    for (int cc = 0; cc < NCHUNK; ++cc) {
        const int c0 = cc * 32;
        if (cc) __syncthreads();
        for (int i = tid; i < 4 * 6 * 58; i += 256) {
            int xx = i % 58, r = i / 58, y = r % 6, cg = r / 6;
            int gh = gh0 + y - 1, gw = xx - 1;
            bool ok = ((unsigned)gh < 56u) & ((unsigned)gw < 56u);
            const float* src = x + ((size_t)(bb * CIN + c0 + cg * 8) * HWDIM + gh) * HWDIM + gw;
            short8 v;
#pragma unroll
            for (int k = 0; k < 8; ++k) v[k] = f2bf(ok ? src[k * HWSZ] : 0.f);
            *(short8*)&sh_halo[(y * 58 + xx) * 32 + ((cg ^ ((xx >> 1) & 3)) << 3)] = v;
        }
        for (int i = tid; i < 9 * 64 * 4; i += 256) {
            int cg = i & 3, off = (i >> 2) % 9, m = i / 36;
            const float* src = w + (size_t)(o0 + m) * KWT + (c0 + cg * 8) * 9 + off;
            short8 v;
#pragma unroll
            for (int k = 0; k < 8; ++k) v[k] = f2bf(src[k * 9]);
            *(short8*)&sh_w[(off * 64 + m) * 32 + ((cg ^ ((m >> 1) & 3)) << 3)] = v;
        }
        __syncthreads();
#pragma unroll
        for (int off = 0; off < 9; ++off) {
            const int di = off / 3, dj = off % 3;
            short8 a[2];
#pragma unroll
            for (int mt = 0; mt < 2; ++mt) {
                int m = wm * 32 + mt * 16 + col;
                a[mt] = *(const short8*)&sh_w[(off * 64 + m) * 32 + ((g ^ ((m >> 1) & 3)) << 3)];
            }
#pragma unroll
            for (int nt = 0; nt < 7; ++nt) {
                int yy = ly[nt] + di, xpp = lx[nt] + dj;
                short8 bfr = *(const short8*)&sh_halo[(yy * 58 + xpp) * 32 + ((g ^ ((xpp >> 1) & 3)) << 3)];
                acc[0][nt] = __builtin_amdgcn_mfma_f32_16x16x32_bf16(a[0], bfr, acc[0][nt], 0, 0, 0);
                acc[1][nt] = __builtin_amdgcn_mfma_f32_16x16x32_bf16(a[1], bfr, acc[1][nt], 0, 0, 0);
            }
        }
    }
#pragma unroll
    for (int mt = 0; mt < 2; ++mt) {
        int o = o0 + wm * 32 + mt * 16 + g * 4;
#pragma unroll
        for (int nt = 0; nt < 7; ++nt) {
            int l = wn * 112 + nt * 16 + col;
            int h = gh0 + l / 56, ww = l % 56;
            size_t base = ((size_t)(bb * COUTN + o) * HWDIM + h) * HWDIM + ww;
            floatx4 v = acc[mt][nt];
#pragma unroll
            for (int r2 = 0; r2 < 4; ++r2)
                out[base + (size_t)r2 * HWSZ] = v[r2] + bias[o + r2];
        }
    }
}

extern "C" void kernel_launch(void* const* d_in, const int* in_sizes, int n_in,
                              void* d_out, int out_size, void* d_ws, size_t ws_size,
                              hipStream_t stream) {
    const float* x  = (const float*)d_in[0];
    const float* wt = (const float*)d_in[1];
    const float* bi = (const float*)d_in[2];
    float* out = (float*)d_out;

    if (ws_size >= WS_NEEDED) {
        short* wpk = (short*)d_ws;
        int tot = 6 * 9 * 192 * 4;
        pack_w<<<(tot + 255) / 256, 256, 0, stream>>>(wt, wpk);
        conv_fused<<<dim3(28, 32), dim3(256), 0, stream>>>(x, wpk, bi, out);
    } else {
        conv3x3_fb<<<dim3(14, 3, 32), dim3(256), 0, stream>>>(x, wt, bi, out);
    }
}